// Round 8
// baseline (508.596 us; speedup 1.0000x reference)
//
#include <hip/hip_runtime.h>

#define DI __device__ __forceinline__

typedef float f32x4 __attribute__((ext_vector_type(4)));
typedef float f4    __attribute__((ext_vector_type(4)));
typedef _Float16 h8 __attribute__((ext_vector_type(8)));
typedef _Float16 h4 __attribute__((ext_vector_type(4)));

// sizes
#define SEQL 512
#define BATCH 256
#define INF 300
#define HID 256
#define N2 512   // 2*HID
#define KP 320   // INF padded to multiple of 64

// pre3 layout: element (t, j, b) at byte
//   t*262144 + (j>>4)*8192 + b*32 + (j&15)*2       (f16)

// tanh = 1 - 2/(1+exp2(x*2*log2e)); exp2->inf => 1, exp2->0 => -1.
DI float ftanh(float x) {
    float e = __builtin_amdgcn_exp2f(x * 2.8853900817779268f);
    return fmaf(-2.0f, __builtin_amdgcn_rcpf(e + 1.0f), 1.0f);
}

// ---------------- prep: build WTs2 in gemm-LDS chunk order + bcat ----------------
// WTs2: [jn(2)][s(5)][c(2048)] 16B chunks. Chunk c: jt=c>>7, kk=(c>>6)&1, lg=(c>>4)&3,
// lj=c&15 holds Wcat[k = s*64+kk*32+lg*8+i][j = jn*256+jt*16+lj], i=0..7 (0 if k>=300).
__global__ void prep_kernel(const float* __restrict__ W1x, const float* __restrict__ W2x,
                            const float* __restrict__ b1, const float* __restrict__ b2,
                            _Float16* __restrict__ WTs2, float* __restrict__ bcat)
{
    int c = blockIdx.x * 256 + threadIdx.x;
    if (c < 2 * 5 * 2048) {
        int jn = c / (5 * 2048);
        int r = c - jn * (5 * 2048);
        int s = r >> 11, cc = r & 2047;
        int jt = cc >> 7, kk = (cc >> 6) & 1, lg = (cc >> 4) & 3, lj = cc & 15;
        int j = jn * 256 + jt * 16 + lj;
        int k0 = s * 64 + kk * 32 + lg * 8;
        const float* W = (j < HID) ? W1x : W2x;
        int jj = (j < HID) ? j : j - HID;
        h8 v;
#pragma unroll
        for (int i = 0; i < 8; ++i)
            v[i] = (k0 + i < INF) ? (_Float16)W[(k0 + i) * HID + jj] : (_Float16)0.f;
        ((h8*)WTs2)[c] = v;
    }
    if (c < N2) bcat[c] = (c < HID) ? b1[c] : b2[c - HID];
}

// ---------------- GEMM: pre3 = x @ Wcat + bcat ----------------
// 128m x 256j tile, 8 waves (2m x 4j), BK=64, 2048 blocks, XCD-grouped swizzle.
// LDS chunk layout [tile16][kk][lane][16B]: all fragment reads are base + lane*16
// (conflict-free); A-stage writes are wave-contiguous ds_write_b128.
__global__ __launch_bounds__(512, 2) void gemm_pre(
    const float* __restrict__ x, const _Float16* __restrict__ WTs2,
    const float* __restrict__ bcat, _Float16* __restrict__ pre3)
{
    __shared__ _Float16 Ab[1024 * 8];  // 16KB: x tile  [mt(8)][kk(2)][lg(4)][lj(16)] chunks
    __shared__ _Float16 Bb[2048 * 8];  // 32KB: W tile  [jt(16)][kk(2)][lg(4)][lj(16)] chunks
    const int tid = threadIdx.x;
    const int w = tid >> 6, l = tid & 63;
    const int lj = l & 15, lg = l >> 4;
    const int bid = blockIdx.x;
    const int xcd = bid & 7;
    const int idx0 = bid >> 3;
    const int jn = idx0 & 1;                 // j half (256 j each)
    const int bm = xcd * 128 + (idx0 >> 1);  // m tile [0,1024)
    const size_t m0 = (size_t)bm * 128;
    const int j0b = jn * 256;
    const int wj = (w >> 1) * 64, wm2 = (w & 1) * 64;

    f32x4 acc[4][4];  // [jt][mt]
#pragma unroll
    for (int a = 0; a < 4; ++a)
#pragma unroll
        for (int b = 0; b < 4; ++b) acc[a][b] = f32x4{0.f, 0.f, 0.f, 0.f};

    const _Float16* Wsrc = WTs2 + (size_t)jn * (5 * 2048 * 8);
    // A-stage per-thread constants: mt_g = w, m row = w*16 + lj
    const int am = w * 16 + lj;
    const float* xp = x + (m0 + am) * INF;
    const int kAo = lg * 8;
    char* AbC = (char*)Ab;
    char* BbC = (char*)Bb;

    for (int s = 0; s < 5; ++s) {
        // W tile: 4 rounds x 512 lanes x 16B = 32KB, lane-linear into chunk layout
#pragma unroll
        for (int q = 0; q < 4; ++q) {
            const _Float16* src = Wsrc + ((size_t)s * 2048 + q * 512 + w * 64 + l) * 8;
            _Float16* dst = &Bb[(q * 512 + w * 64) * 8];  // wave-uniform base
            __builtin_amdgcn_global_load_lds(
                (const __attribute__((address_space(1))) void*)src,
                (__attribute__((address_space(3))) void*)dst, 16, 0, 0);
        }
        // x tile: thread -> chunks (w*128 + l) [kk=0] and (w*128 + 64 + l) [kk=1]
        {
            const int kA = s * 64 + kAo;       // kk=0 chunk: k = kA..kA+7 (always < 300)
            f4 a0 = *(const f4*)(xp + kA);
            f4 a1 = *(const f4*)(xp + kA + 4);
            h8 v0;
#pragma unroll
            for (int i = 0; i < 4; ++i) { v0[i] = (_Float16)a0[i]; v0[4 + i] = (_Float16)a1[i]; }
            h8 v1;
            if (s < 4) {
                f4 b0 = *(const f4*)(xp + kA + 32);
                f4 b1 = *(const f4*)(xp + kA + 36);
#pragma unroll
                for (int i = 0; i < 4; ++i) { v1[i] = (_Float16)b0[i]; v1[4 + i] = (_Float16)b1[i]; }
            } else {
                const int k1 = kA + 32;        // 288..319: guard
#pragma unroll
                for (int i = 0; i < 8; ++i)
                    v1[i] = (k1 + i < INF) ? (_Float16)xp[k1 + i] : (_Float16)0.f;
            }
            *(h8*)(AbC + (w * 128 + l) * 16) = v0;
            *(h8*)(AbC + (w * 128 + 64 + l) * 16) = v1;
        }
        __syncthreads();
#pragma unroll
        for (int kk = 0; kk < 2; ++kk) {
            h8 aw[4], bx[4];
#pragma unroll
            for (int jt = 0; jt < 4; ++jt)
                aw[jt] = *(const h8*)(BbC + ((((wj >> 4) + jt) * 2 + kk) * 1024 + l * 16));
#pragma unroll
            for (int mt = 0; mt < 4; ++mt)
                bx[mt] = *(const h8*)(AbC + ((((wm2 >> 4) + mt) * 2 + kk) * 1024 + l * 16));
#pragma unroll
            for (int jt = 0; jt < 4; ++jt)
#pragma unroll
                for (int mt = 0; mt < 4; ++mt)
                    acc[jt][mt] = __builtin_amdgcn_mfma_f32_16x16x32_f16(aw[jt], bx[mt], acc[jt][mt], 0, 0, 0);
        }
        __syncthreads();
    }
    // epilogue: bias + 16 coalesced 8B stores into pre3
    f4 bias4[4];
#pragma unroll
    for (int jt = 0; jt < 4; ++jt)
        bias4[jt] = *(const f4*)(bcat + j0b + wj + jt * 16 + lg * 4);
    char* prc = (char*)pre3;
#pragma unroll
    for (int jt = 0; jt < 4; ++jt) {
        int slab = (j0b + wj + jt * 16) >> 4;
#pragma unroll
        for (int mt = 0; mt < 4; ++mt) {
            int M = (int)m0 + wm2 + mt * 16;
            size_t byte = (size_t)(M >> 8) * 262144 + (size_t)slab * 8192
                        + (size_t)((M & 255) + lj) * 32 + (size_t)lg * 8;
            h4 o;
#pragma unroll
            for (int i = 0; i < 4; ++i)
                o[i] = (_Float16)(acc[jt][mt][i] + bias4[jt][i]);
            *(h4*)(prc + byte) = o;
        }
    }
}

// ---------------- recurrence: 32 blocks x 8 waves (2/SIMD), 32 j per wave ----------------
// (unchanged from R7 — verified)
__global__ __launch_bounds__(512, 2) void rnn_scan(
    const float* __restrict__ W1h, const float* __restrict__ W2h,
    const _Float16* __restrict__ pre3, float* __restrict__ hcat)
{
    __shared__ char hbs[16384];  // [2][8192]
    char* hbc = hbs;
    const int tid = threadIdx.x;
    const int w = tid >> 6, l = tid & 63;
    const int lj = l & 15, lg = l >> 4;
    const int dir = blockIdx.x & 1;
    const int b0 = (int)(blockIdx.x >> 1) * 16;
    const float* Wh = dir ? W2h : W1h;
    const int j0 = w * 32;
    const int dirOff = dir ? HID : 0;

    h8 afrag[2][8];
#pragma unroll
    for (int jt = 0; jt < 2; ++jt) {
        int jc = j0 + jt * 16 + lj;
#pragma unroll
        for (int kk = 0; kk < 8; ++kk) {
            h8 t;
#pragma unroll
            for (int i = 0; i < 8; ++i) t[i] = (_Float16)Wh[(kk * 32 + lg * 8 + i) * HID + jc];
            afrag[jt][kk] = t;
        }
    }

    const unsigned rb = (unsigned)l * 16;
    const unsigned wb0 = (unsigned)w * 1024 + (unsigned)(lg >> 1) * 256
                       + (unsigned)lj * 16 + (unsigned)(lg & 1) * 8;

    ((h8*)hbs)[tid] = h8{0, 0, 0, 0, 0, 0, 0, 0};
    __syncthreads();

    const long long sb = dir ? -262144LL : 262144LL;
    const char* pp = (const char*)pre3 + (long long)(dir ? (SEQL - 1) : 0) * 262144
                   + (long long)dir * 131072
                   + (long long)w * 16384 + (long long)(b0 + lj) * 32 + lg * 8;
    h4 pA[2], pB[2];
#pragma unroll
    for (int jt = 0; jt < 2; ++jt) pA[jt] = *(const h4*)(pp + jt * 8192);
    pp += sb;
#pragma unroll
    for (int jt = 0; jt < 2; ++jt) pB[jt] = *(const h4*)(pp + jt * 8192);
    pp += sb;

#define RNN_STEP(RB, WB, P, DO_PF)                                                    \
    do {                                                                              \
        h8 bf[8];                                                                     \
        _Pragma("unroll")                                                             \
        for (int kk = 0; kk < 8; ++kk)                                                \
            bf[kk] = *(const h8*)(hbc + (RB) + kk * 1024 + rb);                       \
        f32x4 acc0, acc1;                                                             \
        _Pragma("unroll")                                                             \
        for (int i = 0; i < 4; ++i) { acc0[i] = (float)P[0][i]; acc1[i] = (float)P[1][i]; } \
        if (DO_PF) {                                                                  \
            P[0] = *(const h4*)(pp);                                                  \
            P[1] = *(const h4*)(pp + 8192);                                           \
            pp += sb;                                                                 \
        }                                                                             \
        _Pragma("unroll")                                                             \
        for (int kk = 0; kk < 8; ++kk)                                                \
            acc0 = __builtin_amdgcn_mfma_f32_16x16x32_f16(afrag[0][kk], bf[kk], acc0, 0, 0, 0); \
        h4 o0;                                                                        \
        _Pragma("unroll")                                                             \
        for (int i = 0; i < 4; ++i) o0[i] = (_Float16)ftanh(acc0[i]);                 \
        *(h4*)(hbc + (WB) + wb0) = o0;                                                \
        _Pragma("unroll")                                                             \
        for (int kk = 0; kk < 8; ++kk)                                                \
            acc1 = __builtin_amdgcn_mfma_f32_16x16x32_f16(afrag[1][kk], bf[kk], acc1, 0, 0, 0); \
        h4 o1;                                                                        \
        _Pragma("unroll")                                                             \
        for (int i = 0; i < 4; ++i) o1[i] = (_Float16)ftanh(acc1[i]);                 \
        *(h4*)(hbc + (WB) + wb0 + 512) = o1;                                          \
        __builtin_amdgcn_sched_barrier(0);                                            \
        asm volatile("s_waitcnt lgkmcnt(0)" ::: "memory");                            \
        __builtin_amdgcn_s_barrier();                                                 \
        __builtin_amdgcn_sched_barrier(0);                                            \
    } while (0)

    for (int tp = 0; tp < 255; ++tp) {
        RNN_STEP(0, 8192, pA, 1);
        RNN_STEP(8192, 0, pB, 1);
    }
    RNN_STEP(0, 8192, pA, 0);

    {
        f32x4 acc0, acc1;
#pragma unroll
        for (int i = 0; i < 4; ++i) { acc0[i] = (float)pB[0][i]; acc1[i] = (float)pB[1][i]; }
        h8 bf[8];
#pragma unroll
        for (int kk = 0; kk < 8; ++kk)
            bf[kk] = *(const h8*)(hbc + 8192 + kk * 1024 + rb);
#pragma unroll
        for (int kk = 0; kk < 8; ++kk) {
            acc0 = __builtin_amdgcn_mfma_f32_16x16x32_f16(afrag[0][kk], bf[kk], acc0, 0, 0, 0);
            acc1 = __builtin_amdgcn_mfma_f32_16x16x32_f16(afrag[1][kk], bf[kk], acc1, 0, 0, 0);
        }
        f4 v0, v1;
#pragma unroll
        for (int i = 0; i < 4; ++i) { v0[i] = ftanh(acc0[i]); v1[i] = ftanh(acc1[i]); }
        float* hc = hcat + (size_t)(b0 + lj) * N2 + dirOff + j0 + lg * 4;
        *(f4*)hc = v0;
        *(f4*)(hc + 16) = v1;
    }
#undef RNN_STEP
}

// ---------------- head: 64 blocks x 4 batch-rows (unchanged from R7) ----------------
__global__ __launch_bounds__(256) void head_mlp(
    const float* __restrict__ hcat,
    const float* __restrict__ fc1w, const float* __restrict__ fc1b,
    const float* __restrict__ fc2w, const float* __restrict__ fc2b,
    const float* __restrict__ fsw, const float* __restrict__ fsb,
    float* __restrict__ out)
{
    __shared__ float hs[4 * 512];
    __shared__ float y1[4 * 512];
    __shared__ float y2[4 * 256];
    const int tid = threadIdx.x;
    const int b0 = blockIdx.x * 4;
    const int r = tid >> 6;
    const int lane = tid & 63;

#pragma unroll
    for (int c = 0; c < 2; ++c)
        ((f4*)hs)[c * 256 + tid] = ((const f4*)(hcat + (size_t)b0 * N2))[c * 256 + tid];
    __syncthreads();

    {
        const int j0 = lane * 8;
        f4 a0 = *(const f4*)(fc1b + j0);
        f4 a1 = *(const f4*)(fc1b + j0 + 4);
        for (int k = 0; k < 512; ++k) {
            float h = hs[r * 512 + k];
            f4 w0 = *(const f4*)(fc1w + (size_t)k * 512 + j0);
            f4 w1 = *(const f4*)(fc1w + (size_t)k * 512 + j0 + 4);
#pragma unroll
            for (int i = 0; i < 4; ++i) { a0[i] = fmaf(h, w0[i], a0[i]); a1[i] = fmaf(h, w1[i], a1[i]); }
        }
#pragma unroll
        for (int i = 0; i < 4; ++i) {
            y1[r * 512 + j0 + i]     = fmaxf(a0[i], 0.f);
            y1[r * 512 + j0 + 4 + i] = fmaxf(a1[i], 0.f);
        }
    }
    __syncthreads();

    {
        const int j2 = lane * 4;
        f4 a = *(const f4*)(fc2b + j2);
        for (int k = 0; k < 512; ++k) {
            float yv = y1[r * 512 + k];
            f4 w = *(const f4*)(fc2w + (size_t)k * 256 + j2);
#pragma unroll
            for (int i = 0; i < 4; ++i) a[i] = fmaf(yv, w[i], a[i]);
        }
#pragma unroll
        for (int i = 0; i < 4; ++i) y2[r * 256 + j2 + i] = fmaxf(a[i], 0.f);
    }
    __syncthreads();

    {
        float p = 0.f;
#pragma unroll
        for (int u = 0; u < 4; ++u)
            p = fmaf(y2[r * 256 + lane + u * 64], fsw[lane + u * 64], p);
#pragma unroll
        for (int off = 32; off > 0; off >>= 1) p += __shfl_down(p, off);
        if (lane == 0) out[b0 + r] = ftanh(p + fsb[0]);
    }
}

extern "C" void kernel_launch(void* const* d_in, const int* in_sizes, int n_in,
                              void* d_out, int out_size, void* d_ws, size_t ws_size,
                              hipStream_t stream)
{
    const float* x    = (const float*)d_in[0];
    const float* W1x  = (const float*)d_in[1];
    const float* W1h  = (const float*)d_in[2];
    const float* b1   = (const float*)d_in[3];
    const float* W2x  = (const float*)d_in[4];
    const float* W2h  = (const float*)d_in[5];
    const float* b2   = (const float*)d_in[6];
    const float* fc1w = (const float*)d_in[7];
    const float* fc1b = (const float*)d_in[8];
    const float* fc2w = (const float*)d_in[9];
    const float* fc2b = (const float*)d_in[10];
    const float* fsw  = (const float*)d_in[11];
    const float* fsb  = (const float*)d_in[12];

    char* ws = (char*)d_ws;
    size_t off = 0;
    _Float16* WTs2 = (_Float16*)(ws + off); off += (size_t)2 * 5 * 2048 * 8 * sizeof(_Float16); // 327,680
    float* bcat    = (float*)(ws + off);    off += (size_t)N2 * sizeof(float);
    float* hcat    = (float*)(ws + off);    off += (size_t)BATCH * N2 * sizeof(float);
    _Float16* pre3 = (_Float16*)(ws + off); off += (size_t)SEQL * BATCH * N2 * sizeof(_Float16);
    if (off > ws_size) return;

    prep_kernel<<<80, 256, 0, stream>>>(W1x, W2x, b1, b2, WTs2, bcat);
    gemm_pre<<<2048, 512, 0, stream>>>(x, WTs2, bcat, pre3);
    rnn_scan<<<(BATCH / 16) * 2, 512, 0, stream>>>(W1h, W2h, pre3, hcat);
    head_mlp<<<64, 256, 0, stream>>>(hcat, fc1w, fc1b, fc2w, fc2b, fsw, fsb, (float*)d_out);
}